// Round 2
// baseline (14974.103 us; speedup 1.0000x reference)
//
#include <hip/hip_runtime.h>

// ---------------- constants ----------------
// B=2048, K_OTH=16, K_LANE=32, N_OTH=32768, N_LANE=65536
// T=20 (hist/av), T_PRED=30, H=25, gates=100, NH=5, FO=5
//
// node id ranges (encoder): [0,2048) agent | [2048,4096) av | [4096,36864) others | [36864,102400) lanes
// ws layout (floats): ag_h @0 (51200) | ag_c @51200 | av_c @102400 | ot_c @153600 (819200)
//                     | ln_c @972800 (1638400) | env_code @2611200 (51200)  -> total 2662400 floats (~10.7MB)
// out layout: predict [2048*30*2) @0, env_lane_info [2048*25] @122880

__device__ __forceinline__ float frcp(float x) { return __builtin_amdgcn_rcpf(x); }
__device__ __forceinline__ float fsig(float x) { return frcp(1.f + __expf(-x)); }
__device__ __forceinline__ float ftanh(float x) { return 1.f - 2.f * frcp(1.f + __expf(2.f * x)); }

// ---------------- encoder: thread per node, weights in LDS ----------------
__global__ __launch_bounds__(256) void enc_kernel(
    const float* __restrict__ agent, const float* __restrict__ av,
    const float* __restrict__ oth,   const float* __restrict__ lane,
    const float* __restrict__ agWih, const float* __restrict__ agWhh, const float* __restrict__ agB,
    const float* __restrict__ avWih, const float* __restrict__ avWhh, const float* __restrict__ avB,
    const float* __restrict__ otWih, const float* __restrict__ otWhh, const float* __restrict__ otB,
    float* __restrict__ ws)
{
    __shared__ float Wsh[100 * 28];   // Whh rows padded 25->28 (16B aligned), pads = 0
    __shared__ float Wish[200];       // Wih [100][2]
    __shared__ float bsh[100];

    const int tid = threadIdx.x;
    const int gid = blockIdx.x * 256 + tid;

    int task;
    if (gid < 2048) task = 0;
    else if (gid < 4096) task = 1;
    else if (gid < 36864) task = 2;
    else task = 3;                    // lanes use the *agent* encoder (faithful to source bug)

    const float* Wih; const float* Whh; const float* Bp;
    if (task == 1)      { Wih = avWih; Whh = avWhh; Bp = avB; }
    else if (task == 2) { Wih = otWih; Whh = otWhh; Bp = otB; }
    else                { Wih = agWih; Whh = agWhh; Bp = agB; }

    for (int i = tid; i < 2800; i += 256) {
        int r = i / 28, cc = i - r * 28;
        Wsh[i] = (cc < 25) ? Whh[r * 25 + cc] : 0.f;
    }
    for (int i = tid; i < 200; i += 256) Wish[i] = Wih[i];
    for (int i = tid; i < 100; i += 256) bsh[i] = Bp[i];
    __syncthreads();

    const float* xp; int n;
    if (task == 0)      { n = gid;          xp = agent + n * 100; } // [50][2], use first 20 steps
    else if (task == 1) { n = gid - 2048;   xp = av   + n * 40; }
    else if (task == 2) { n = gid - 4096;   xp = oth  + n * 40; }
    else                { n = gid - 36864;  xp = lane + n * 40; }

    float h[28], c[25], hn[25];
#pragma unroll
    for (int k = 0; k < 28; ++k) h[k] = 0.f;
#pragma unroll
    for (int k = 0; k < 25; ++k) c[k] = 0.f;

    for (int t = 0; t < 20; ++t) {
        const float2 xv = *reinterpret_cast<const float2*>(xp + 2 * t);
        const float x0 = xv.x, x1 = xv.y;
#pragma unroll
        for (int u = 0; u < 25; ++u) {
            float g[4];
#pragma unroll
            for (int r = 0; r < 4; ++r) {
                const int row = u + 25 * r;
                float acc = bsh[row] + Wish[2 * row] * x0 + Wish[2 * row + 1] * x1;
                const float4* wr = reinterpret_cast<const float4*>(&Wsh[row * 28]);
#pragma unroll
                for (int jj = 0; jj < 7; ++jj) {
                    float4 w = wr[jj];
                    acc += w.x * h[4 * jj] + w.y * h[4 * jj + 1] + w.z * h[4 * jj + 2] + w.w * h[4 * jj + 3];
                }
                g[r] = acc;
            }
            const float iv = fsig(g[0]);
            const float fv = fsig(g[1]);
            const float gv = ftanh(g[2]);
            const float ov = fsig(g[3]);
            c[u]  = fv * c[u] + iv * gv;
            hn[u] = ov * ftanh(c[u]);
        }
#pragma unroll
        for (int u = 0; u < 25; ++u) h[u] = hn[u];
    }

    float* dst_c; float* dst_h = nullptr;
    if (task == 0)      { dst_h = ws + 0      + n * 25; dst_c = ws + 51200  + n * 25; }
    else if (task == 1) { dst_c = ws + 102400 + n * 25; }
    else if (task == 2) { dst_c = ws + 153600 + n * 25; }
    else                { dst_c = ws + 972800 + n * 25; }
#pragma unroll
    for (int u = 0; u < 25; ++u) dst_c[u] = c[u];
    if (task == 0) {
#pragma unroll
        for (int u = 0; u < 25; ++u) dst_h[u] = h[u];
    }
}

// ---------------- GAT + env_lane_info: one block per env ----------------
__global__ __launch_bounds__(256) void gat_kernel(
    const float* __restrict__ ws,
    const float* __restrict__ gavW, const float* __restrict__ gavAl, const float* __restrict__ gavAr, const float* __restrict__ gavB,
    const float* __restrict__ gotW, const float* __restrict__ gotAl, const float* __restrict__ gotAr, const float* __restrict__ gotB,
    const float* __restrict__ glnW, const float* __restrict__ glnAl, const float* __restrict__ glnAr, const float* __restrict__ glnB,
    float* __restrict__ envcode, float* __restrict__ lane_out)
{
    __shared__ float X[50 * 25];   // 0: ag_c, 1: av_c, 2..17: ot srcs, 18..49: ln srcs
    __shared__ float F[52 * 25];   // 0: fs_av, 1: fd_av(unused), 2: fd_ot, 3: fd_ln, 4..19: fs_ot, 20..51: fs_ln
    __shared__ float er[10];       // [conv(ot=0,ln=1)][head]
    __shared__ float Eo[16 * 5];
    __shared__ float El[32 * 5];

    const int tid = threadIdx.x;
    const int b = blockIdx.x;
    const float* agc = ws + 51200;
    const float* avc = ws + 102400;
    const float* otc = ws + 153600;
    const float* lnc = ws + 972800;

    for (int i = tid; i < 1250; i += 256) {
        int r = i / 25, k = i - r * 25;
        float v;
        if (r == 0)      v = agc[b * 25 + k];
        else if (r == 1) v = avc[b * 25 + k];
        else if (r < 18) v = otc[(b * 16 + (r - 2)) * 25 + k];
        else             v = lnc[(b * 32 + (r - 18)) * 25 + k];
        X[i] = v;
    }
    __syncthreads();

    for (int d = tid; d < 1300; d += 256) {
        int row = d / 25, o = d - row * 25;
        const float* W; const float* xs;
        if (row == 0)      { W = gavW; xs = &X[1 * 25]; }
        else if (row == 1) { W = gavW; xs = &X[0]; }
        else if (row == 2) { W = gotW; xs = &X[0]; }
        else if (row == 3) { W = glnW; xs = &X[0]; }
        else if (row < 20) { W = gotW; xs = &X[(2 + row - 4) * 25]; }
        else               { W = glnW; xs = &X[(18 + row - 20) * 25]; }
        float acc = 0.f;
#pragma unroll
        for (int k = 0; k < 25; ++k) acc += W[o * 25 + k] * xs[k];
        F[row * 25 + o] = acc;
    }
    __syncthreads();

    if (tid < 10) {
        int conv = tid / 5, nn = tid - conv * 5;
        const float* ar = conv ? glnAr : gotAr;
        const float* fd = &F[(2 + conv) * 25];
        float acc = 0.f;
#pragma unroll
        for (int f = 0; f < 5; ++f) acc += fd[nn * 5 + f] * ar[nn * 5 + f];
        er[tid] = acc;
    }
    __syncthreads();

    for (int d = tid; d < 240; d += 256) {
        if (d < 80) {
            int i = d / 5, nn = d - i * 5;
            const float* fsrow = &F[(4 + i) * 25];
            float acc = er[nn];
#pragma unroll
            for (int f = 0; f < 5; ++f) acc += fsrow[nn * 5 + f] * gotAl[nn * 5 + f];
            Eo[d] = (acc > 0.f) ? acc : 0.2f * acc;
        } else {
            int d2 = d - 80;
            int i = d2 / 5, nn = d2 - i * 5;
            const float* fsrow = &F[(20 + i) * 25];
            float acc = er[5 + nn];
#pragma unroll
            for (int f = 0; f < 5; ++f) acc += fsrow[nn * 5 + f] * glnAl[nn * 5 + f];
            El[d2] = (acc > 0.f) ? acc : 0.2f * acc;
        }
    }
    __syncthreads();

    if (tid < 10) {
        int conv = tid / 5, nn = tid - conv * 5;
        if (conv == 0) {
            float m = -1e30f;
            for (int i = 0; i < 16; ++i) m = fmaxf(m, Eo[i * 5 + nn]);
            float s = 0.f;
            for (int i = 0; i < 16; ++i) s += __expf(Eo[i * 5 + nn] - m);
            float inv = frcp(s);
            for (int i = 0; i < 16; ++i) Eo[i * 5 + nn] = __expf(Eo[i * 5 + nn] - m) * inv;
        } else {
            float m = -1e30f;
            for (int i = 0; i < 32; ++i) m = fmaxf(m, El[i * 5 + nn]);
            float s = 0.f;
            for (int i = 0; i < 32; ++i) s += __expf(El[i * 5 + nn] - m);
            float inv = frcp(s);
            for (int i = 0; i < 32; ++i) El[i * 5 + nn] = __expf(El[i * 5 + nn] - m) * inv;
        }
    }
    __syncthreads();

    if (tid < 25) {
        const int o = tid, nn = o / 5;
        float v_av = F[o] + gavB[o];
        float s = 0.f;
        for (int i = 0; i < 16; ++i) s += Eo[i * 5 + nn] * F[(4 + i) * 25 + o];
        float v_ot = s + gotB[o];
        s = 0.f;
        for (int i = 0; i < 32; ++i) s += El[i * 5 + nn] * F[(20 + i) * 25 + o];
        float v_ln = s + glnB[o];
        envcode[b * 25 + o] = (v_av + v_ot + v_ln) * (1.f / 3.f);
        float m = 0.f;
        for (int i = 0; i < 32; ++i) m += X[(18 + i) * 25 + o];
        lane_out[b * 25 + o] = m * (1.f / 32.f);
    }
}

// ---------------- decoder: 25 lanes per env, 2 envs per wave, reg weights ----------------
__global__ __launch_bounds__(256) void dec_kernel(
    const float* __restrict__ ws,
    const float* __restrict__ deWih, const float* __restrict__ deWhh, const float* __restrict__ deB,
    const float* __restrict__ linW,  const float* __restrict__ linB,
    float* __restrict__ out)
{
    __shared__ float hbuf[8][28];
    const int tid  = threadIdx.x;
    const int lane = tid & 63;
    const int half = lane >> 5;
    const int u    = lane & 31;
    const int u2   = (u < 25) ? u : 0;
    const bool act = (u < 25);
    const int wglob = (blockIdx.x * 256 + tid) >> 6;
    const int b = wglob * 2 + half;                 // env id
    const int envloc = ((tid >> 6) << 1) + half;    // 0..7 within block

    float U[4][25], Wi[4], Bb[4];
#pragma unroll
    for (int r = 0; r < 4; ++r) {
        const int row = u2 + 25 * r;
#pragma unroll
        for (int k = 0; k < 25; ++k) U[r][k] = deWhh[row * 25 + k];
        Wi[r] = deWih[row];
        Bb[r] = deB[row];
    }
    const int j = u & 1;
    float lw[25];
#pragma unroll
    for (int k = 0; k < 25; ++k) lw[k] = linW[j * 25 + k];
    const float lb = linB[j];

    const float* agh = ws;
    const float* agc = ws + 51200;
    const float* env = ws + 2611200;

    float h[25];
#pragma unroll
    for (int k = 0; k < 25; ++k) h[k] = agh[b * 25 + k];
    float c_own = agc[b * 25 + u2] + env[b * 25 + u2];

    for (int t = 0; t < 30; ++t) {
        const float tt = 0.1f * (float)t;
        float g[4];
#pragma unroll
        for (int r = 0; r < 4; ++r) {
            float acc = Bb[r] + Wi[r] * tt;
#pragma unroll
            for (int k = 0; k < 25; ++k) acc += U[r][k] * h[k];
            g[r] = acc;
        }
        const float iv = fsig(g[0]);
        const float fv = fsig(g[1]);
        const float gv = ftanh(g[2]);
        const float ov = fsig(g[3]);
        c_own = fv * c_own + iv * gv;
        const float ho = ov * ftanh(c_own);
        if (act) hbuf[envloc][u] = ho;
        __builtin_amdgcn_wave_barrier();   // intra-wave LDS exchange; LDS is in-order per wave
#pragma unroll
        for (int k = 0; k < 25; ++k) h[k] = hbuf[envloc][k];
        float ov2 = lb;
#pragma unroll
        for (int k = 0; k < 25; ++k) ov2 += lw[k] * h[k];
        if (u < 2) out[b * 60 + t * 2 + u] = ov2;
    }
}

// ---------------- launch ----------------
extern "C" void kernel_launch(void* const* d_in, const int* in_sizes, int n_in,
                              void* d_out, int out_size, void* d_ws, size_t ws_size,
                              hipStream_t stream)
{
    const float* agent = (const float*)d_in[0];
    const float* av    = (const float*)d_in[1];
    const float* oth   = (const float*)d_in[2];
    const float* lane  = (const float*)d_in[3];
    const float* agWih = (const float*)d_in[4];
    const float* agWhh = (const float*)d_in[5];
    const float* agB   = (const float*)d_in[6];
    const float* avWih = (const float*)d_in[7];
    const float* avWhh = (const float*)d_in[8];
    const float* avB   = (const float*)d_in[9];
    const float* otWih = (const float*)d_in[10];
    const float* otWhh = (const float*)d_in[11];
    const float* otB   = (const float*)d_in[12];
    const float* deWih = (const float*)d_in[13];
    const float* deWhh = (const float*)d_in[14];
    const float* deB   = (const float*)d_in[15];
    const float* linW  = (const float*)d_in[16];
    const float* linB  = (const float*)d_in[17];
    const float* gavW  = (const float*)d_in[18];
    const float* gavAl = (const float*)d_in[19];
    const float* gavAr = (const float*)d_in[20];
    const float* gavB  = (const float*)d_in[21];
    const float* gotW  = (const float*)d_in[22];
    const float* gotAl = (const float*)d_in[23];
    const float* gotAr = (const float*)d_in[24];
    const float* gotB  = (const float*)d_in[25];
    const float* glnW  = (const float*)d_in[26];
    const float* glnAl = (const float*)d_in[27];
    const float* glnAr = (const float*)d_in[28];
    const float* glnB  = (const float*)d_in[29];
    // d_in[30]=others_dst, d_in[31]=lane_dst: implicit (i/16, i/32), not needed

    float* out = (float*)d_out;
    float* ws  = (float*)d_ws;

    enc_kernel<<<400, 256, 0, stream>>>(agent, av, oth, lane,
                                        agWih, agWhh, agB,
                                        avWih, avWhh, avB,
                                        otWih, otWhh, otB, ws);

    gat_kernel<<<2048, 256, 0, stream>>>(ws,
                                         gavW, gavAl, gavAr, gavB,
                                         gotW, gotAl, gotAr, gotB,
                                         glnW, glnAl, glnAr, glnB,
                                         ws + 2611200, out + 122880);

    dec_kernel<<<256, 256, 0, stream>>>(ws, deWih, deWhh, deB, linW, linB, out);
}

// Round 6
// 437.902 us; speedup vs baseline: 34.1951x; 34.1951x over previous
//
#include <hip/hip_runtime.h>

// ---------------- constants ----------------
// B=2048, K_OTH=16, K_LANE=32, N_OTH=32768, N_LANE=65536
// T=20 (hist/av), T_PRED=30, H=25, gates=100, NH=5, FO=5
//
// node id ranges: [0,2048) agent | [2048,4096) av | [4096,36864) others | [36864,102400) lanes
// ws layout (floats): ag_h @0 | ag_c @51200 | av_c @102400 | ot_c @153600 | ln_c @972800 | env_code @2611200
// out layout: predict [2048*30*2] @0, env_lane_info [2048*25] @122880

__device__ __forceinline__ float frcp(float x) { return __builtin_amdgcn_rcpf(x); }
__device__ __forceinline__ float fsig(float x) { return frcp(1.f + __expf(-x)); }
__device__ __forceinline__ float ftanh(float x) { return 1.f - 2.f * frcp(1.f + __expf(2.f * x)); }

// ---------------- encoder: unit-per-lane, 2 nodes/wave, weights in registers ----------------
// 2048 waves total (512 blocks x 4 waves); wave W owns node-pairs [25W, 25W+25).
// Lane u (<25) owns hidden unit u of its half's node: 4 gate rows in VGPRs.
// h state lives in a per-half 28-float LDS row, rewritten each step (dec_kernel pattern).
__global__ __launch_bounds__(256) void enc_kernel(
    const float* __restrict__ agent, const float* __restrict__ av,
    const float* __restrict__ oth,   const float* __restrict__ lane,
    const float* __restrict__ agWih, const float* __restrict__ agWhh, const float* __restrict__ agB,
    const float* __restrict__ avWih, const float* __restrict__ avWhh, const float* __restrict__ avB,
    const float* __restrict__ otWih, const float* __restrict__ otWhh, const float* __restrict__ otB,
    float* __restrict__ ws)
{
    __shared__ float hbuf[4][2][28];   // [wave][half][unit], rows 112B -> 16B aligned

    const int tid   = threadIdx.x;
    const int wv    = tid >> 6;
    const int lanei = tid & 63;
    const int half  = lanei >> 5;
    const int u     = lanei & 31;
    const bool act  = (u < 25);
    const int u2    = act ? u : 0;

    // zero the pad once (units 25..27)
    if (u >= 25 && u < 28) hbuf[wv][half][u] = 0.f;

    const int W  = blockIdx.x * 4 + wv;   // global wave id, 0..2047
    const int p0 = W * 25;
    const int p1 = p0 + 25;               // 2048*25 = 51200 pairs exactly

    int curTask = -1;
    float U[4][28], Wi0[4], Wi1[4], Bb[4];

#pragma unroll 1
    for (int p = p0; p < p1; ++p) {
        const int n = 2 * p + half;       // node id; both halves share the task (boundaries even)

        int task;
        if (n < 2048) task = 0;
        else if (n < 4096) task = 1;
        else if (n < 36864) task = 2;
        else task = 3;                    // lanes use the *agent* encoder (faithful to source bug)

        if (task != curTask) {            // wave-uniform
            curTask = task;
            const float* Wih; const float* Whh; const float* Bp;
            if (task == 1)      { Wih = avWih; Whh = avWhh; Bp = avB; }
            else if (task == 2) { Wih = otWih; Whh = otWhh; Bp = otB; }
            else                { Wih = agWih; Whh = agWhh; Bp = agB; }
#pragma unroll
            for (int r = 0; r < 4; ++r) {
                const int row = u2 + 25 * r;
#pragma unroll
                for (int k = 0; k < 25; ++k) U[r][k] = Whh[row * 25 + k];
#pragma unroll
                for (int k = 25; k < 28; ++k) U[r][k] = 0.f;
                Wi0[r] = Wih[2 * row];
                Wi1[r] = Wih[2 * row + 1];
                Bb[r]  = Bp[row];
            }
        }

        const float* xp;
        if (task == 0)      xp = agent + n * 100;            // [50][2], first 20 steps
        else if (task == 1) xp = av   + (n - 2048)  * 40;
        else if (task == 2) xp = oth  + (n - 4096)  * 40;
        else                xp = lane + (n - 36864) * 40;

        // lane t (<20) holds the step-t input pair
        float2 xt = make_float2(0.f, 0.f);
        if (u < 20) xt = *reinterpret_cast<const float2*>(xp + 2 * u);

        float c = 0.f, ho = 0.f;
        float4 h4[7];
#pragma unroll
        for (int j = 0; j < 7; ++j) h4[j] = make_float4(0.f, 0.f, 0.f, 0.f);

#pragma unroll 1
        for (int t = 0; t < 20; ++t) {
            const float x0 = __shfl(xt.x, half * 32 + t, 64);
            const float x1 = __shfl(xt.y, half * 32 + t, 64);
            float g[4];
#pragma unroll
            for (int r = 0; r < 4; ++r) {
                float acc = Bb[r] + Wi0[r] * x0 + Wi1[r] * x1;
#pragma unroll
                for (int j = 0; j < 7; ++j) {
                    acc += U[r][4 * j]     * h4[j].x + U[r][4 * j + 1] * h4[j].y
                         + U[r][4 * j + 2] * h4[j].z + U[r][4 * j + 3] * h4[j].w;
                }
                g[r] = acc;
            }
            const float iv = fsig(g[0]);
            const float fv = fsig(g[1]);
            const float gv = ftanh(g[2]);
            const float ov = fsig(g[3]);
            c  = fv * c + iv * gv;
            ho = ov * ftanh(c);

            if (act) hbuf[wv][half][u] = ho;   // publish h(t+1)
            __builtin_amdgcn_wave_barrier();   // intra-wave LDS exchange (in-order per wave)
#pragma unroll
            for (int j = 0; j < 7; ++j)
                h4[j] = *reinterpret_cast<const float4*>(&hbuf[wv][half][4 * j]);
        }

        if (act) {
            if (task == 0) {
                ws[n * 25 + u]          = ho;   // ag_h
                ws[51200 + n * 25 + u]  = c;    // ag_c
            } else if (task == 1) {
                ws[102400 + (n - 2048) * 25 + u] = c;
            } else if (task == 2) {
                ws[153600 + (n - 4096) * 25 + u] = c;
            } else {
                ws[972800 + (n - 36864) * 25 + u] = c;
            }
        }
    }
}

// ---------------- GAT + env_lane_info: one block per env ----------------
__global__ __launch_bounds__(256) void gat_kernel(
    const float* __restrict__ ws,
    const float* __restrict__ gavW, const float* __restrict__ gavAl, const float* __restrict__ gavAr, const float* __restrict__ gavB,
    const float* __restrict__ gotW, const float* __restrict__ gotAl, const float* __restrict__ gotAr, const float* __restrict__ gotB,
    const float* __restrict__ glnW, const float* __restrict__ glnAl, const float* __restrict__ glnAr, const float* __restrict__ glnB,
    float* __restrict__ envcode, float* __restrict__ lane_out)
{
    __shared__ float X[50 * 25];   // 0: ag_c, 1: av_c, 2..17: ot srcs, 18..49: ln srcs
    __shared__ float F[52 * 25];   // 0: fs_av, 1: fd_av(unused), 2: fd_ot, 3: fd_ln, 4..19: fs_ot, 20..51: fs_ln
    __shared__ float er[10];       // [conv(ot=0,ln=1)][head]
    __shared__ float Eo[16 * 5];
    __shared__ float El[32 * 5];

    const int tid = threadIdx.x;
    const int b = blockIdx.x;
    const float* agc = ws + 51200;
    const float* avc = ws + 102400;
    const float* otc = ws + 153600;
    const float* lnc = ws + 972800;

    for (int i = tid; i < 1250; i += 256) {
        int r = i / 25, k = i - r * 25;
        float v;
        if (r == 0)      v = agc[b * 25 + k];
        else if (r == 1) v = avc[b * 25 + k];
        else if (r < 18) v = otc[(b * 16 + (r - 2)) * 25 + k];
        else             v = lnc[(b * 32 + (r - 18)) * 25 + k];
        X[i] = v;
    }
    __syncthreads();

    for (int d = tid; d < 1300; d += 256) {
        int row = d / 25, o = d - row * 25;
        const float* W; const float* xs;
        if (row == 0)      { W = gavW; xs = &X[1 * 25]; }
        else if (row == 1) { W = gavW; xs = &X[0]; }
        else if (row == 2) { W = gotW; xs = &X[0]; }
        else if (row == 3) { W = glnW; xs = &X[0]; }
        else if (row < 20) { W = gotW; xs = &X[(2 + row - 4) * 25]; }
        else               { W = glnW; xs = &X[(18 + row - 20) * 25]; }
        float acc = 0.f;
#pragma unroll
        for (int k = 0; k < 25; ++k) acc += W[o * 25 + k] * xs[k];
        F[row * 25 + o] = acc;
    }
    __syncthreads();

    if (tid < 10) {
        int conv = tid / 5, nn = tid - conv * 5;
        const float* ar = conv ? glnAr : gotAr;
        const float* fd = &F[(2 + conv) * 25];
        float acc = 0.f;
#pragma unroll
        for (int f = 0; f < 5; ++f) acc += fd[nn * 5 + f] * ar[nn * 5 + f];
        er[tid] = acc;
    }
    __syncthreads();

    for (int d = tid; d < 240; d += 256) {
        if (d < 80) {
            int i = d / 5, nn = d - i * 5;
            const float* fsrow = &F[(4 + i) * 25];
            float acc = er[nn];
#pragma unroll
            for (int f = 0; f < 5; ++f) acc += fsrow[nn * 5 + f] * gotAl[nn * 5 + f];
            Eo[d] = (acc > 0.f) ? acc : 0.2f * acc;
        } else {
            int d2 = d - 80;
            int i = d2 / 5, nn = d2 - i * 5;
            const float* fsrow = &F[(20 + i) * 25];
            float acc = er[5 + nn];
#pragma unroll
            for (int f = 0; f < 5; ++f) acc += fsrow[nn * 5 + f] * glnAl[nn * 5 + f];
            El[d2] = (acc > 0.f) ? acc : 0.2f * acc;
        }
    }
    __syncthreads();

    if (tid < 10) {
        int conv = tid / 5, nn = tid - conv * 5;
        if (conv == 0) {
            float m = -1e30f;
            for (int i = 0; i < 16; ++i) m = fmaxf(m, Eo[i * 5 + nn]);
            float s = 0.f;
            for (int i = 0; i < 16; ++i) s += __expf(Eo[i * 5 + nn] - m);
            float inv = frcp(s);
            for (int i = 0; i < 16; ++i) Eo[i * 5 + nn] = __expf(Eo[i * 5 + nn] - m) * inv;
        } else {
            float m = -1e30f;
            for (int i = 0; i < 32; ++i) m = fmaxf(m, El[i * 5 + nn]);
            float s = 0.f;
            for (int i = 0; i < 32; ++i) s += __expf(El[i * 5 + nn] - m);
            float inv = frcp(s);
            for (int i = 0; i < 32; ++i) El[i * 5 + nn] = __expf(El[i * 5 + nn] - m) * inv;
        }
    }
    __syncthreads();

    if (tid < 25) {
        const int o = tid, nn = o / 5;
        float v_av = F[o] + gavB[o];
        float s = 0.f;
        for (int i = 0; i < 16; ++i) s += Eo[i * 5 + nn] * F[(4 + i) * 25 + o];
        float v_ot = s + gotB[o];
        s = 0.f;
        for (int i = 0; i < 32; ++i) s += El[i * 5 + nn] * F[(20 + i) * 25 + o];
        float v_ln = s + glnB[o];
        envcode[b * 25 + o] = (v_av + v_ot + v_ln) * (1.f / 3.f);
        float m = 0.f;
        for (int i = 0; i < 32; ++i) m += X[(18 + i) * 25 + o];
        lane_out[b * 25 + o] = m * (1.f / 32.f);
    }
}

// ---------------- decoder: 25 lanes per env, 2 envs per wave, reg weights ----------------
__global__ __launch_bounds__(256) void dec_kernel(
    const float* __restrict__ ws,
    const float* __restrict__ deWih, const float* __restrict__ deWhh, const float* __restrict__ deB,
    const float* __restrict__ linW,  const float* __restrict__ linB,
    float* __restrict__ out)
{
    __shared__ float hbuf[8][28];
    const int tid  = threadIdx.x;
    const int lane = tid & 63;
    const int half = lane >> 5;
    const int u    = lane & 31;
    const int u2   = (u < 25) ? u : 0;
    const bool act = (u < 25);
    const int wglob = (blockIdx.x * 256 + tid) >> 6;
    const int b = wglob * 2 + half;                 // env id
    const int envloc = ((tid >> 6) << 1) + half;    // 0..7 within block

    float U[4][25], Wi[4], Bb[4];
#pragma unroll
    for (int r = 0; r < 4; ++r) {
        const int row = u2 + 25 * r;
#pragma unroll
        for (int k = 0; k < 25; ++k) U[r][k] = deWhh[row * 25 + k];
        Wi[r] = deWih[row];
        Bb[r] = deB[row];
    }
    const int j = u & 1;
    float lw[25];
#pragma unroll
    for (int k = 0; k < 25; ++k) lw[k] = linW[j * 25 + k];
    const float lb = linB[j];

    const float* agh = ws;
    const float* agc = ws + 51200;
    const float* env = ws + 2611200;

    float h[25];
#pragma unroll
    for (int k = 0; k < 25; ++k) h[k] = agh[b * 25 + k];
    float c_own = agc[b * 25 + u2] + env[b * 25 + u2];

    for (int t = 0; t < 30; ++t) {
        const float tt = 0.1f * (float)t;
        float g[4];
#pragma unroll
        for (int r = 0; r < 4; ++r) {
            float acc = Bb[r] + Wi[r] * tt;
#pragma unroll
            for (int k = 0; k < 25; ++k) acc += U[r][k] * h[k];
            g[r] = acc;
        }
        const float iv = fsig(g[0]);
        const float fv = fsig(g[1]);
        const float gv = ftanh(g[2]);
        const float ov = fsig(g[3]);
        c_own = fv * c_own + iv * gv;
        const float ho = ov * ftanh(c_own);
        if (act) hbuf[envloc][u] = ho;
        __builtin_amdgcn_wave_barrier();   // intra-wave LDS exchange; LDS is in-order per wave
#pragma unroll
        for (int k = 0; k < 25; ++k) h[k] = hbuf[envloc][k];
        float ov2 = lb;
#pragma unroll
        for (int k = 0; k < 25; ++k) ov2 += lw[k] * h[k];
        if (u < 2) out[b * 60 + t * 2 + u] = ov2;
    }
}

// ---------------- launch ----------------
extern "C" void kernel_launch(void* const* d_in, const int* in_sizes, int n_in,
                              void* d_out, int out_size, void* d_ws, size_t ws_size,
                              hipStream_t stream)
{
    const float* agent = (const float*)d_in[0];
    const float* av    = (const float*)d_in[1];
    const float* oth   = (const float*)d_in[2];
    const float* lane  = (const float*)d_in[3];
    const float* agWih = (const float*)d_in[4];
    const float* agWhh = (const float*)d_in[5];
    const float* agB   = (const float*)d_in[6];
    const float* avWih = (const float*)d_in[7];
    const float* avWhh = (const float*)d_in[8];
    const float* avB   = (const float*)d_in[9];
    const float* otWih = (const float*)d_in[10];
    const float* otWhh = (const float*)d_in[11];
    const float* otB   = (const float*)d_in[12];
    const float* deWih = (const float*)d_in[13];
    const float* deWhh = (const float*)d_in[14];
    const float* deB   = (const float*)d_in[15];
    const float* linW  = (const float*)d_in[16];
    const float* linB  = (const float*)d_in[17];
    const float* gavW  = (const float*)d_in[18];
    const float* gavAl = (const float*)d_in[19];
    const float* gavAr = (const float*)d_in[20];
    const float* gavB  = (const float*)d_in[21];
    const float* gotW  = (const float*)d_in[22];
    const float* gotAl = (const float*)d_in[23];
    const float* gotAr = (const float*)d_in[24];
    const float* gotB  = (const float*)d_in[25];
    const float* glnW  = (const float*)d_in[26];
    const float* glnAl = (const float*)d_in[27];
    const float* glnAr = (const float*)d_in[28];
    const float* glnB  = (const float*)d_in[29];
    // d_in[30]=others_dst, d_in[31]=lane_dst: implicit (i/16, i/32), not needed

    float* out = (float*)d_out;
    float* ws  = (float*)d_ws;

    enc_kernel<<<512, 256, 0, stream>>>(agent, av, oth, lane,
                                        agWih, agWhh, agB,
                                        avWih, avWhh, avB,
                                        otWih, otWhh, otB, ws);

    gat_kernel<<<2048, 256, 0, stream>>>(ws,
                                         gavW, gavAl, gavAr, gavB,
                                         gotW, gotAl, gotAr, gotB,
                                         glnW, glnAl, glnAr, glnB,
                                         ws + 2611200, out + 122880);

    dec_kernel<<<256, 256, 0, stream>>>(ws, deWih, deWhh, deB, linW, linB, out);
}

// Round 8
// 386.147 us; speedup vs baseline: 38.7782x; 1.1340x over previous
//
#include <hip/hip_runtime.h>

// ---------------- constants ----------------
// B=2048, K_OTH=16, K_LANE=32, N_OTH=32768, N_LANE=65536
// T=20 (hist/av), T_PRED=30, H=25, gates=100, NH=5, FO=5
//
// node id ranges: [0,2048) agent | [2048,4096) av | [4096,36864) others | [36864,102400) lanes
// ws layout (floats): ag_h @0 | ag_c @51200 | av_c @102400 | ot_c @153600 | ln_c @972800 | env_code @2611200
// out layout: predict [2048*30*2] @0, env_lane_info [2048*25] @122880

__device__ __forceinline__ float frcp(float x) { return __builtin_amdgcn_rcpf(x); }
__device__ __forceinline__ float fsig(float x) { return frcp(1.f + __expf(-x)); }
__device__ __forceinline__ float ftanh(float x) { return 1.f - 2.f * frcp(1.f + __expf(2.f * x)); }

// ---------------- encoder: unit-per-lane, 2 nodes/wave, weights in registers ----------------
// 4096 waves (1024 blocks x 4 waves) -> 4 waves/SIMD at VGPR<=128.
// Wave W owns 13 pairs (W<2048) or 12 pairs (W>=2048); 2048*13+2048*12 = 51200 pairs.
// Lane u (<25) owns hidden unit u of its half's node: 4 gate rows in VGPRs (U[4][25]).
// h state lives in a per-half 28-float LDS row, rewritten each step.
__global__ __launch_bounds__(256) void enc_kernel(
    const float* __restrict__ agent, const float* __restrict__ av,
    const float* __restrict__ oth,   const float* __restrict__ lane,
    const float* __restrict__ agWih, const float* __restrict__ agWhh, const float* __restrict__ agB,
    const float* __restrict__ avWih, const float* __restrict__ avWhh, const float* __restrict__ avB,
    const float* __restrict__ otWih, const float* __restrict__ otWhh, const float* __restrict__ otB,
    float* __restrict__ ws)
{
    __shared__ float hbuf[4][2][28];   // [wave][half][unit], rows 112B -> 16B aligned

    const int tid   = threadIdx.x;
    const int wv    = tid >> 6;
    const int lanei = tid & 63;
    const int half  = lanei >> 5;
    const int u     = lanei & 31;
    const bool act  = (u < 25);
    const int u2    = act ? u : 0;

    // zero the pad once (units 25..27)
    if (u >= 25 && u < 28) hbuf[wv][half][u] = 0.f;

    const int W = blockIdx.x * 4 + wv;    // global wave id, 0..4095
    int p0, p1;
    if (W < 2048) { p0 = W * 13;                 p1 = p0 + 13; }
    else          { p0 = 26624 + (W - 2048) * 12; p1 = p0 + 12; }

    int curTask = -1;
    float U[4][25], Wi0[4], Wi1[4], Bb[4];

#pragma unroll 1
    for (int p = p0; p < p1; ++p) {
        const int n = 2 * p + half;       // node id; both halves share the task (boundaries even)

        int task;
        if (n < 2048) task = 0;
        else if (n < 4096) task = 1;
        else if (n < 36864) task = 2;
        else task = 3;                    // lanes use the *agent* encoder (faithful to source bug)

        if (task != curTask) {            // wave-uniform
            curTask = task;
            const float* Wih; const float* Whh; const float* Bp;
            if (task == 1)      { Wih = avWih; Whh = avWhh; Bp = avB; }
            else if (task == 2) { Wih = otWih; Whh = otWhh; Bp = otB; }
            else                { Wih = agWih; Whh = agWhh; Bp = agB; }
#pragma unroll
            for (int r = 0; r < 4; ++r) {
                const int row = u2 + 25 * r;
#pragma unroll
                for (int k = 0; k < 25; ++k) U[r][k] = Whh[row * 25 + k];
                Wi0[r] = Wih[2 * row];
                Wi1[r] = Wih[2 * row + 1];
                Bb[r]  = Bp[row];
            }
        }

        const float* xp;
        if (task == 0)      xp = agent + n * 100;            // [50][2], first 20 steps
        else if (task == 1) xp = av   + (n - 2048)  * 40;
        else if (task == 2) xp = oth  + (n - 4096)  * 40;
        else                xp = lane + (n - 36864) * 40;

        // lane t (<20) holds the step-t input pair
        float2 xt = make_float2(0.f, 0.f);
        if (u < 20) xt = *reinterpret_cast<const float2*>(xp + 2 * u);

        float c = 0.f, ho = 0.f;
        float4 h4[7];
#pragma unroll
        for (int j = 0; j < 7; ++j) h4[j] = make_float4(0.f, 0.f, 0.f, 0.f);

#pragma unroll 1
        for (int t = 0; t < 20; ++t) {
            const float x0 = __shfl(xt.x, half * 32 + t, 64);
            const float x1 = __shfl(xt.y, half * 32 + t, 64);
            float g[4];
#pragma unroll
            for (int r = 0; r < 4; ++r) {
                float acc = Bb[r] + Wi0[r] * x0 + Wi1[r] * x1;
#pragma unroll
                for (int j = 0; j < 6; ++j) {
                    acc += U[r][4 * j]     * h4[j].x + U[r][4 * j + 1] * h4[j].y
                         + U[r][4 * j + 2] * h4[j].z + U[r][4 * j + 3] * h4[j].w;
                }
                acc += U[r][24] * h4[6].x;
                g[r] = acc;
            }
            const float iv = fsig(g[0]);
            const float fv = fsig(g[1]);
            const float gv = ftanh(g[2]);
            const float ov = fsig(g[3]);
            c  = fv * c + iv * gv;
            ho = ov * ftanh(c);

            if (act) hbuf[wv][half][u] = ho;   // publish h(t+1)
            __builtin_amdgcn_wave_barrier();   // intra-wave LDS exchange (in-order per wave)
#pragma unroll
            for (int j = 0; j < 7; ++j)
                h4[j] = *reinterpret_cast<const float4*>(&hbuf[wv][half][4 * j]);
        }

        if (act) {
            if (task == 0) {
                ws[n * 25 + u]          = ho;   // ag_h
                ws[51200 + n * 25 + u]  = c;    // ag_c
            } else if (task == 1) {
                ws[102400 + (n - 2048) * 25 + u] = c;
            } else if (task == 2) {
                ws[153600 + (n - 4096) * 25 + u] = c;
            } else {
                ws[972800 + (n - 36864) * 25 + u] = c;
            }
        }
    }
}

// ---------------- GAT + env_lane_info: one block per env ----------------
__global__ __launch_bounds__(256) void gat_kernel(
    const float* __restrict__ ws,
    const float* __restrict__ gavW, const float* __restrict__ gavAl, const float* __restrict__ gavAr, const float* __restrict__ gavB,
    const float* __restrict__ gotW, const float* __restrict__ gotAl, const float* __restrict__ gotAr, const float* __restrict__ gotB,
    const float* __restrict__ glnW, const float* __restrict__ glnAl, const float* __restrict__ glnAr, const float* __restrict__ glnB,
    float* __restrict__ envcode, float* __restrict__ lane_out)
{
    __shared__ float X[50 * 25];   // 0: ag_c, 1: av_c, 2..17: ot srcs, 18..49: ln srcs
    __shared__ float F[52 * 25];   // 0: fs_av, 1: fd_av(unused), 2: fd_ot, 3: fd_ln, 4..19: fs_ot, 20..51: fs_ln
    __shared__ float er[10];       // [conv(ot=0,ln=1)][head]
    __shared__ float Eo[16 * 5];
    __shared__ float El[32 * 5];

    const int tid = threadIdx.x;
    const int b = blockIdx.x;
    const float* agc = ws + 51200;
    const float* avc = ws + 102400;
    const float* otc = ws + 153600;
    const float* lnc = ws + 972800;

    for (int i = tid; i < 1250; i += 256) {
        int r = i / 25, k = i - r * 25;
        float v;
        if (r == 0)      v = agc[b * 25 + k];
        else if (r == 1) v = avc[b * 25 + k];
        else if (r < 18) v = otc[(b * 16 + (r - 2)) * 25 + k];
        else             v = lnc[(b * 32 + (r - 18)) * 25 + k];
        X[i] = v;
    }
    __syncthreads();

    for (int d = tid; d < 1300; d += 256) {
        int row = d / 25, o = d - row * 25;
        const float* W; const float* xs;
        if (row == 0)      { W = gavW; xs = &X[1 * 25]; }
        else if (row == 1) { W = gavW; xs = &X[0]; }
        else if (row == 2) { W = gotW; xs = &X[0]; }
        else if (row == 3) { W = glnW; xs = &X[0]; }
        else if (row < 20) { W = gotW; xs = &X[(2 + row - 4) * 25]; }
        else               { W = glnW; xs = &X[(18 + row - 20) * 25]; }
        float acc = 0.f;
#pragma unroll
        for (int k = 0; k < 25; ++k) acc += W[o * 25 + k] * xs[k];
        F[row * 25 + o] = acc;
    }
    __syncthreads();

    if (tid < 10) {
        int conv = tid / 5, nn = tid - conv * 5;
        const float* ar = conv ? glnAr : gotAr;
        const float* fd = &F[(2 + conv) * 25];
        float acc = 0.f;
#pragma unroll
        for (int f = 0; f < 5; ++f) acc += fd[nn * 5 + f] * ar[nn * 5 + f];
        er[tid] = acc;
    }
    __syncthreads();

    for (int d = tid; d < 240; d += 256) {
        if (d < 80) {
            int i = d / 5, nn = d - i * 5;
            const float* fsrow = &F[(4 + i) * 25];
            float acc = er[nn];
#pragma unroll
            for (int f = 0; f < 5; ++f) acc += fsrow[nn * 5 + f] * gotAl[nn * 5 + f];
            Eo[d] = (acc > 0.f) ? acc : 0.2f * acc;
        } else {
            int d2 = d - 80;
            int i = d2 / 5, nn = d2 - i * 5;
            const float* fsrow = &F[(20 + i) * 25];
            float acc = er[5 + nn];
#pragma unroll
            for (int f = 0; f < 5; ++f) acc += fsrow[nn * 5 + f] * glnAl[nn * 5 + f];
            El[d2] = (acc > 0.f) ? acc : 0.2f * acc;
        }
    }
    __syncthreads();

    if (tid < 10) {
        int conv = tid / 5, nn = tid - conv * 5;
        if (conv == 0) {
            float m = -1e30f;
            for (int i = 0; i < 16; ++i) m = fmaxf(m, Eo[i * 5 + nn]);
            float s = 0.f;
            for (int i = 0; i < 16; ++i) s += __expf(Eo[i * 5 + nn] - m);
            float inv = frcp(s);
            for (int i = 0; i < 16; ++i) Eo[i * 5 + nn] = __expf(Eo[i * 5 + nn] - m) * inv;
        } else {
            float m = -1e30f;
            for (int i = 0; i < 32; ++i) m = fmaxf(m, El[i * 5 + nn]);
            float s = 0.f;
            for (int i = 0; i < 32; ++i) s += __expf(El[i * 5 + nn] - m);
            float inv = frcp(s);
            for (int i = 0; i < 32; ++i) El[i * 5 + nn] = __expf(El[i * 5 + nn] - m) * inv;
        }
    }
    __syncthreads();

    if (tid < 25) {
        const int o = tid, nn = o / 5;
        float v_av = F[o] + gavB[o];
        float s = 0.f;
        for (int i = 0; i < 16; ++i) s += Eo[i * 5 + nn] * F[(4 + i) * 25 + o];
        float v_ot = s + gotB[o];
        s = 0.f;
        for (int i = 0; i < 32; ++i) s += El[i * 5 + nn] * F[(20 + i) * 25 + o];
        float v_ln = s + glnB[o];
        envcode[b * 25 + o] = (v_av + v_ot + v_ln) * (1.f / 3.f);
        float m = 0.f;
        for (int i = 0; i < 32; ++i) m += X[(18 + i) * 25 + o];
        lane_out[b * 25 + o] = m * (1.f / 32.f);
    }
}

// ---------------- decoder: 25 lanes per env, 2 envs per wave, reg weights ----------------
__global__ __launch_bounds__(256) void dec_kernel(
    const float* __restrict__ ws,
    const float* __restrict__ deWih, const float* __restrict__ deWhh, const float* __restrict__ deB,
    const float* __restrict__ linW,  const float* __restrict__ linB,
    float* __restrict__ out)
{
    __shared__ float hbuf[8][28];
    const int tid  = threadIdx.x;
    const int lane = tid & 63;
    const int half = lane >> 5;
    const int u    = lane & 31;
    const int u2   = (u < 25) ? u : 0;
    const bool act = (u < 25);
    const int wglob = (blockIdx.x * 256 + tid) >> 6;
    const int b = wglob * 2 + half;                 // env id
    const int envloc = ((tid >> 6) << 1) + half;    // 0..7 within block

    float U[4][25], Wi[4], Bb[4];
#pragma unroll
    for (int r = 0; r < 4; ++r) {
        const int row = u2 + 25 * r;
#pragma unroll
        for (int k = 0; k < 25; ++k) U[r][k] = deWhh[row * 25 + k];
        Wi[r] = deWih[row];
        Bb[r] = deB[row];
    }
    const int j = u & 1;
    float lw[25];
#pragma unroll
    for (int k = 0; k < 25; ++k) lw[k] = linW[j * 25 + k];
    const float lb = linB[j];

    const float* agh = ws;
    const float* agc = ws + 51200;
    const float* env = ws + 2611200;

    float h[25];
#pragma unroll
    for (int k = 0; k < 25; ++k) h[k] = agh[b * 25 + k];
    float c_own = agc[b * 25 + u2] + env[b * 25 + u2];

    for (int t = 0; t < 30; ++t) {
        const float tt = 0.1f * (float)t;
        float g[4];
#pragma unroll
        for (int r = 0; r < 4; ++r) {
            float acc = Bb[r] + Wi[r] * tt;
#pragma unroll
            for (int k = 0; k < 25; ++k) acc += U[r][k] * h[k];
            g[r] = acc;
        }
        const float iv = fsig(g[0]);
        const float fv = fsig(g[1]);
        const float gv = ftanh(g[2]);
        const float ov = fsig(g[3]);
        c_own = fv * c_own + iv * gv;
        const float ho = ov * ftanh(c_own);
        if (act) hbuf[envloc][u] = ho;
        __builtin_amdgcn_wave_barrier();   // intra-wave LDS exchange; LDS is in-order per wave
#pragma unroll
        for (int k = 0; k < 25; ++k) h[k] = hbuf[envloc][k];
        float ov2 = lb;
#pragma unroll
        for (int k = 0; k < 25; ++k) ov2 += lw[k] * h[k];
        if (u < 2) out[b * 60 + t * 2 + u] = ov2;
    }
}

// ---------------- launch ----------------
extern "C" void kernel_launch(void* const* d_in, const int* in_sizes, int n_in,
                              void* d_out, int out_size, void* d_ws, size_t ws_size,
                              hipStream_t stream)
{
    const float* agent = (const float*)d_in[0];
    const float* av    = (const float*)d_in[1];
    const float* oth   = (const float*)d_in[2];
    const float* lane  = (const float*)d_in[3];
    const float* agWih = (const float*)d_in[4];
    const float* agWhh = (const float*)d_in[5];
    const float* agB   = (const float*)d_in[6];
    const float* avWih = (const float*)d_in[7];
    const float* avWhh = (const float*)d_in[8];
    const float* avB   = (const float*)d_in[9];
    const float* otWih = (const float*)d_in[10];
    const float* otWhh = (const float*)d_in[11];
    const float* otB   = (const float*)d_in[12];
    const float* deWih = (const float*)d_in[13];
    const float* deWhh = (const float*)d_in[14];
    const float* deB   = (const float*)d_in[15];
    const float* linW  = (const float*)d_in[16];
    const float* linB  = (const float*)d_in[17];
    const float* gavW  = (const float*)d_in[18];
    const float* gavAl = (const float*)d_in[19];
    const float* gavAr = (const float*)d_in[20];
    const float* gavB  = (const float*)d_in[21];
    const float* gotW  = (const float*)d_in[22];
    const float* gotAl = (const float*)d_in[23];
    const float* gotAr = (const float*)d_in[24];
    const float* gotB  = (const float*)d_in[25];
    const float* glnW  = (const float*)d_in[26];
    const float* glnAl = (const float*)d_in[27];
    const float* glnAr = (const float*)d_in[28];
    const float* glnB  = (const float*)d_in[29];
    // d_in[30]=others_dst, d_in[31]=lane_dst: implicit (i/16, i/32), not needed

    float* out = (float*)d_out;
    float* ws  = (float*)d_ws;

    enc_kernel<<<1024, 256, 0, stream>>>(agent, av, oth, lane,
                                         agWih, agWhh, agB,
                                         avWih, avWhh, avB,
                                         otWih, otWhh, otB, ws);

    gat_kernel<<<2048, 256, 0, stream>>>(ws,
                                         gavW, gavAl, gavAr, gavB,
                                         gotW, gotAl, gotAr, gotB,
                                         glnW, glnAl, glnAr, glnB,
                                         ws + 2611200, out + 122880);

    dec_kernel<<<256, 256, 0, stream>>>(ws, deWih, deWhh, deB, linW, linB, out);
}